// Round 12
// baseline (235.612 us; speedup 1.0000x reference)
//
#include <hip/hip_runtime.h>

#define N_NODES 40000
#define N_EDGES 640000
#define DIM 128
#define N_LAYERS 3
#define STRIDE 64  // padded-CSR row stride; P(deg>64) ~ e^-40 under Poisson(16)

typedef _Float16 half_t;
typedef __attribute__((ext_vector_type(8))) _Float16 f16x8_t;
typedef __attribute__((ext_vector_type(4))) float f32x4_t;

// ---------------- fused preprocessing ----------------
// blocks [0, SB): padded-CSR scatter, 2 independent edges per thread (2x atomic MLP)
// blocks [SB, ...): x -> fp16 cast, W[k][n] f32 -> Wt[l][s][n][k] f16 transpose
__global__ void scatterprep_kernel(const int* __restrict__ src, const int* __restrict__ dst,
                                   int* __restrict__ cnt, int* __restrict__ pcsr,
                                   const float* __restrict__ x, half_t* __restrict__ h,
                                   const float* __restrict__ w_self, const float* __restrict__ w_neigh,
                                   half_t* __restrict__ wt) {
    const int HALF = N_EDGES / 2;  // 320000
    const int SB = (HALF + 255) / 256;  // 1250
    if (blockIdx.x < SB) {
        int i = blockIdx.x * 256 + threadIdx.x;
        if (i < HALF) {
            // two independent edge chains -> 2 atomics + 2 scatters in flight
            int d0 = dst[i], d1 = dst[i + HALF];
            int s0 = src[i], s1 = src[i + HALF];
            int p0 = atomicAdd(&cnt[d0], 1);
            int p1 = atomicAdd(&cnt[d1], 1);
            if (p0 < STRIDE) pcsr[d0 * STRIDE + p0] = s0;
            if (p1 < STRIDE) pcsr[d1 * STRIDE + p1] = s1;
        }
        return;
    }
    int i = (blockIdx.x - SB) * 256 + threadIdx.x;
    const int NS = N_NODES * DIM / 8;  // 640000 8-float chunks
    if (i < NS) {
        const float4* p = (const float4*)x + (size_t)i * 2;
        float4 a = p[0], b2 = p[1];
        f16x8_t v;
        v[0] = (half_t)a.x;  v[1] = (half_t)a.y;  v[2] = (half_t)a.z;  v[3] = (half_t)a.w;
        v[4] = (half_t)b2.x; v[5] = (half_t)b2.y; v[6] = (half_t)b2.z; v[7] = (half_t)b2.w;
        *(f16x8_t*)&h[(size_t)i * 8] = v;
    } else {
        int j = i - NS;
        if (j < N_LAYERS * 2 * DIM * DIM) {
            int k = j & (DIM - 1);
            int n = (j >> 7) & (DIM - 1);
            int ls = j >> 14;
            int l = ls >> 1, s = ls & 1;
            const float* W = (s ? w_neigh : w_self) + (size_t)l * DIM * DIM;
            wt[j] = (half_t)W[k * DIM + n];  // transposed: Wt[n][k]
        }
    }
}

// ---------------- mean aggregation: fp16 gather, index-hoisted, grid-strided ----------------
// Upfront per node: lane l holds pcsr[e0+l] and validity (1.0/0.0); chunk loop gets
// both via __shfl (ee <= 63 always since base <= 48), only in-loop mem op = 16B row load.
// fmaf(f32,(float)f16,f32) compiles to v_fma_mix (no separate cvt).
__global__ void agg_kernel(const half_t* __restrict__ h, const int* __restrict__ cnt,
                           const int* __restrict__ pcsr, half_t* __restrict__ agg) {
    const int gw = (blockIdx.x * blockDim.x + threadIdx.x) >> 6;
    const int nw = (gridDim.x * blockDim.x) >> 6;
    const int lane = threadIdx.x & 63;
    const int g = lane >> 4, c = lane & 15;  // edge-group, 16B column chunk

    for (int node = gw; node < N_NODES; node += nw) {
        int deg = cnt[node];
        int nd = deg < STRIDE ? deg : STRIDE;
        int il = (lane < nd) ? pcsr[node * STRIDE + lane] : 0;
        float fl = (lane < nd) ? 1.f : 0.f;

        float acc[8] = {0.f, 0.f, 0.f, 0.f, 0.f, 0.f, 0.f, 0.f};
        for (int base = 0; base < nd; base += 16) {
            float f[4];
            int sidx[4];
            f16x8_t v[4];
#pragma unroll
            for (int s = 0; s < 4; ++s) {
                int ee = base + 4 * s + g;   // <= 63 by construction (base <= 48)
                sidx[s] = __shfl(il, ee, 64);
                f[s] = __shfl(fl, ee, 64);
                v[s] = *(const f16x8_t*)&h[(size_t)sidx[s] * DIM + c * 8];
            }
#pragma unroll
            for (int s = 0; s < 4; ++s)
#pragma unroll
                for (int j = 0; j < 8; ++j)
                    acc[j] = fmaf(f[s], (float)v[s][j], acc[j]);  // -> v_fma_mix
        }
#pragma unroll
        for (int j = 0; j < 8; ++j) {
            acc[j] += __shfl_xor(acc[j], 16, 64);
            acc[j] += __shfl_xor(acc[j], 32, 64);
        }
        if (g == 0) {
            float w = 1.0f / fmaxf((float)deg, 1.0f);
            f16x8_t o;
#pragma unroll
            for (int j = 0; j < 8; ++j) o[j] = (half_t)(acc[j] * w);
            *(f16x8_t*)&agg[(size_t)node * DIM + c * 8] = o;
        }
    }
}

// ---------------- fused dual GEMM, single-pass fp16 MFMA ----------------
// out = h @ Wself + agg @ Wneigh + b. OCCUPANCY FIX (r12): stage Wself and Wneigh
// SEQUENTIALLY through ONE 34.8 KB LDS buffer (stage -> compute -> barrier -> restage)
// -> 4 blocks/CU (vs 2 with the 69.6 KB dual stage), 4 waves/SIMD to hide the
// A-row global-load latency that dominated at 1.25 waves/SIMD.
// Block: 256 thr = 4 waves, 128x128 tile. In-place h update safe (own rows only).
#define LDSN 136  // 128 + 8 pad halves: B-frag reads land 2-way max bank alias (free)
__global__ __launch_bounds__(256) void gemm_kernel(
    half_t* __restrict__ h, const half_t* __restrict__ agg,
    const half_t* __restrict__ wt,  // this layer: [2][128][128] (n-major, k contiguous)
    const float* __restrict__ bias, float* __restrict__ fout,
    int write_f32, int relu) {
    __shared__ half_t sW[DIM][LDSN];  // 34.8 KB, reused for both W halves
    const int tid = threadIdx.x;
    const int wave = tid >> 6, lane = tid & 63;
    const int quad = lane >> 4, m = lane & 15;
    const int rowW = blockIdx.x * 128 + wave * 32;

    f32x4_t acc[2][8];
#pragma unroll
    for (int a = 0; a < 2; ++a)
#pragma unroll
        for (int b = 0; b < 8; ++b) acc[a][b] = {0.f, 0.f, 0.f, 0.f};

#pragma unroll
    for (int s = 0; s < 2; ++s) {
        if (s) __syncthreads();  // previous compute done before overwrite
        // stage W_s: 2048 16B chunks / 256 threads = 8 each
#pragma unroll
        for (int c8 = 0; c8 < 8; ++c8) {
            int c = (c8 << 8) + tid;
            int part = c & 15;   // 16B chunk within 256B row
            int n = c >> 4;      // 0..127
            *(f16x8_t*)&sW[n][part * 8] = *(const f16x8_t*)&wt[(size_t)(s * DIM + n) * DIM + part * 8];
        }
        __syncthreads();

        const half_t* A = s ? agg : h;
#pragma unroll
        for (int k2 = 0; k2 < 4; ++k2) {
            const int kg = (k2 << 5) + quad * 8;
            f16x8_t B[8];
#pragma unroll
            for (int jt = 0; jt < 8; ++jt)
                B[jt] = *(const f16x8_t*)&sW[jt * 16 + m][kg];
#pragma unroll
            for (int rt = 0; rt < 2; ++rt) {
                int r = rowW + rt * 16 + m;
                r = (r < N_NODES) ? r : (N_NODES - 1);  // clamp; stores guarded later
                f16x8_t a = *(const f16x8_t*)&A[(size_t)r * DIM + kg];
#pragma unroll
                for (int jt = 0; jt < 8; ++jt)
                    acc[rt][jt] = __builtin_amdgcn_mfma_f32_16x16x32_f16(a, B[jt], acc[rt][jt], 0, 0, 0);
            }
        }
    }

    // epilogue: C/D layout col=lane&15, row=quad*4+reg  [m89-verified]
#pragma unroll
    for (int rt = 0; rt < 2; ++rt)
#pragma unroll
        for (int jt = 0; jt < 8; ++jt) {
            int col = jt * 16 + m;
            float bv = bias[col];
#pragma unroll
            for (int r4 = 0; r4 < 4; ++r4) {
                int row = rowW + rt * 16 + quad * 4 + r4;
                if (row >= N_NODES) continue;
                float v = acc[rt][jt][r4] + bv;
                if (relu) v = fmaxf(v, 0.f);
                if (write_f32) {
                    fout[(size_t)row * DIM + col] = v;
                } else {
                    h[(size_t)row * DIM + col] = (half_t)v;
                }
            }
        }
}

// ---------------- launch ----------------

extern "C" void kernel_launch(void* const* d_in, const int* in_sizes, int n_in,
                              void* d_out, int out_size, void* d_ws, size_t ws_size,
                              hipStream_t stream) {
    const float* x      = (const float*)d_in[0];
    const int*   src    = (const int*)d_in[1];
    const int*   dst    = (const int*)d_in[2];
    const float* w_self = (const float*)d_in[3];
    const float* w_neigh= (const float*)d_in[4];
    const float* b      = (const float*)d_in[5];
    float* out = (float*)d_out;

    // workspace carve (~31 MB)
    char* ws = (char*)d_ws;
    half_t* h    = (half_t*)ws;  ws += (size_t)N_NODES * DIM * 2;
    half_t* agg  = (half_t*)ws;  ws += (size_t)N_NODES * DIM * 2;
    half_t* wt   = (half_t*)ws;  ws += (size_t)N_LAYERS * 2 * DIM * DIM * 2;
    int*   cnt   = (int*)ws;     ws += (size_t)N_NODES * 4;
    int*   pcsr  = (int*)ws;     ws += (size_t)N_NODES * STRIDE * 4;

    hipMemsetAsync(cnt, 0, (size_t)N_NODES * 4, stream);

    const int SB = (N_EDGES / 2 + 255) / 256;  // 1250
    const int PREP_ITEMS = N_NODES * DIM / 8 + N_LAYERS * 2 * DIM * DIM;
    const int PB = (PREP_ITEMS + 255) / 256;   // 2884
    scatterprep_kernel<<<SB + PB, 256, 0, stream>>>(src, dst, cnt, pcsr,
                                                    x, h, w_self, w_neigh, wt);

    const int GEMM_BLOCKS = (N_NODES + 127) / 128;  // 313
    for (int l = 0; l < N_LAYERS; ++l) {
        agg_kernel<<<2048, 256, 0, stream>>>(h, cnt, pcsr, agg);
        int last = (l == N_LAYERS - 1);
        gemm_kernel<<<GEMM_BLOCKS, 256, 0, stream>>>(
            h, agg, wt + (size_t)l * 2 * DIM * DIM, b + (size_t)l * DIM,
            out, last ? 1 : 0, last ? 0 : 1);
    }
}

// Round 13
// 227.150 us; speedup vs baseline: 1.0373x; 1.0373x over previous
//
#include <hip/hip_runtime.h>

#define N_NODES 40000
#define N_EDGES 640000
#define DIM 128
#define N_LAYERS 3
#define STRIDE 64  // padded-CSR row stride; P(deg>64) ~ e^-40 under Poisson(16)

typedef _Float16 half_t;
typedef __attribute__((ext_vector_type(8))) _Float16 f16x8_t;
typedef __attribute__((ext_vector_type(4))) float f32x4_t;

// ---------------- fused preprocessing ----------------
// blocks [0, SB): padded-CSR scatter, 2 independent edges per thread (2x atomic MLP)
// blocks [SB, ...): x -> fp16 cast, W[k][n] f32 -> Wt[l][s][n][k] f16 transpose
__global__ void scatterprep_kernel(const int* __restrict__ src, const int* __restrict__ dst,
                                   int* __restrict__ cnt, int* __restrict__ pcsr,
                                   const float* __restrict__ x, half_t* __restrict__ h,
                                   const float* __restrict__ w_self, const float* __restrict__ w_neigh,
                                   half_t* __restrict__ wt) {
    const int HALF = N_EDGES / 2;  // 320000
    const int SB = (HALF + 255) / 256;  // 1250
    if (blockIdx.x < SB) {
        int i = blockIdx.x * 256 + threadIdx.x;
        if (i < HALF) {
            // two independent edge chains -> 2 atomics + 2 scatters in flight
            int d0 = dst[i], d1 = dst[i + HALF];
            int s0 = src[i], s1 = src[i + HALF];
            int p0 = atomicAdd(&cnt[d0], 1);
            int p1 = atomicAdd(&cnt[d1], 1);
            if (p0 < STRIDE) pcsr[d0 * STRIDE + p0] = s0;
            if (p1 < STRIDE) pcsr[d1 * STRIDE + p1] = s1;
        }
        return;
    }
    int i = (blockIdx.x - SB) * 256 + threadIdx.x;
    const int NS = N_NODES * DIM / 8;  // 640000 8-float chunks
    if (i < NS) {
        const float4* p = (const float4*)x + (size_t)i * 2;
        float4 a = p[0], b2 = p[1];
        f16x8_t v;
        v[0] = (half_t)a.x;  v[1] = (half_t)a.y;  v[2] = (half_t)a.z;  v[3] = (half_t)a.w;
        v[4] = (half_t)b2.x; v[5] = (half_t)b2.y; v[6] = (half_t)b2.z; v[7] = (half_t)b2.w;
        *(f16x8_t*)&h[(size_t)i * 8] = v;
    } else {
        int j = i - NS;
        if (j < N_LAYERS * 2 * DIM * DIM) {
            int k = j & (DIM - 1);
            int n = (j >> 7) & (DIM - 1);
            int ls = j >> 14;
            int l = ls >> 1, s = ls & 1;
            const float* W = (s ? w_neigh : w_self) + (size_t)l * DIM * DIM;
            wt[j] = (half_t)W[k * DIM + n];  // transposed: Wt[n][k]
        }
    }
}

// ---------------- mean aggregation: fp16 gather, index-hoisted, grid-strided ----------------
// Upfront per node: lane l holds pcsr[e0+l] and validity (1.0/0.0); chunk loop gets
// both via __shfl (ee <= 63 always since base <= 48), only in-loop mem op = 16B row load.
// fmaf(f32,(float)f16,f32) compiles to v_fma_mix (no separate cvt).
__global__ void agg_kernel(const half_t* __restrict__ h, const int* __restrict__ cnt,
                           const int* __restrict__ pcsr, half_t* __restrict__ agg) {
    const int gw = (blockIdx.x * blockDim.x + threadIdx.x) >> 6;
    const int nw = (gridDim.x * blockDim.x) >> 6;
    const int lane = threadIdx.x & 63;
    const int g = lane >> 4, c = lane & 15;  // edge-group, 16B column chunk

    for (int node = gw; node < N_NODES; node += nw) {
        int deg = cnt[node];
        int nd = deg < STRIDE ? deg : STRIDE;
        int il = (lane < nd) ? pcsr[node * STRIDE + lane] : 0;
        float fl = (lane < nd) ? 1.f : 0.f;

        float acc[8] = {0.f, 0.f, 0.f, 0.f, 0.f, 0.f, 0.f, 0.f};
        for (int base = 0; base < nd; base += 16) {
            float f[4];
            int sidx[4];
            f16x8_t v[4];
#pragma unroll
            for (int s = 0; s < 4; ++s) {
                int ee = base + 4 * s + g;   // <= 63 by construction (base <= 48)
                sidx[s] = __shfl(il, ee, 64);
                f[s] = __shfl(fl, ee, 64);
                v[s] = *(const f16x8_t*)&h[(size_t)sidx[s] * DIM + c * 8];
            }
#pragma unroll
            for (int s = 0; s < 4; ++s)
#pragma unroll
                for (int j = 0; j < 8; ++j)
                    acc[j] = fmaf(f[s], (float)v[s][j], acc[j]);  // -> v_fma_mix
        }
#pragma unroll
        for (int j = 0; j < 8; ++j) {
            acc[j] += __shfl_xor(acc[j], 16, 64);
            acc[j] += __shfl_xor(acc[j], 32, 64);
        }
        if (g == 0) {
            float w = 1.0f / fmaxf((float)deg, 1.0f);
            f16x8_t o;
#pragma unroll
            for (int j = 0; j < 8; ++j) o[j] = (half_t)(acc[j] * w);
            *(f16x8_t*)&agg[(size_t)node * DIM + c * 8] = o;
        }
    }
}

// ---------------- fused dual GEMM, single-pass fp16 MFMA ----------------
// out = h @ Wself + agg @ Wneigh + b. r11 shape (dual W stage, 69.6 KB, one barrier,
// 2 blocks/CU) + r13 A-PREFETCH: all 16 A-frag loads (h + agg) are issued BEFORE the
// W staging; their L2/L3 latency hides under the ~16-round stage + barrier instead of
// stalling the MFMA loop. Compute then runs purely from regs + LDS.
// In-place h update safe: each block reads/writes only its own 128 rows.
#define LDSN 136  // 128 + 8 pad halves: B-frag reads land 2-way max bank alias (free)
__global__ __launch_bounds__(256) void gemm_kernel(
    half_t* __restrict__ h, const half_t* __restrict__ agg,
    const half_t* __restrict__ wt,  // this layer: [2][128][128] (n-major, k contiguous)
    const float* __restrict__ bias, float* __restrict__ fout,
    int write_f32, int relu) {
    __shared__ half_t sW[2 * DIM][LDSN];
    const int tid = threadIdx.x;
    const int wave = tid >> 6, lane = tid & 63;
    const int quad = lane >> 4, m = lane & 15;
    const int rowW = blockIdx.x * 128 + wave * 32;

    // ---- A-frag prefetch: 16 independent global loads, issued first ----
    f16x8_t aF[2][2][4];  // [s][rt][k2], 64 VGPRs
#pragma unroll
    for (int s = 0; s < 2; ++s) {
        const half_t* A = s ? agg : h;
#pragma unroll
        for (int rt = 0; rt < 2; ++rt) {
            int r = rowW + rt * 16 + m;
            r = (r < N_NODES) ? r : (N_NODES - 1);  // clamp; stores guarded later
            const half_t* Ar = &A[(size_t)r * DIM + quad * 8];
#pragma unroll
            for (int k2 = 0; k2 < 4; ++k2)
                aF[s][rt][k2] = *(const f16x8_t*)&Ar[k2 << 5];
        }
    }

    // ---- stage both W matrices, full K (4096 16B chunks / 256 threads = 16 each) ----
#pragma unroll
    for (int c4 = 0; c4 < 16; ++c4) {
        int c = (c4 << 8) + tid;
        int part = c & 15;   // 16B chunk within 256B row
        int n = c >> 4;      // 0..255 = s*128+n
        *(f16x8_t*)&sW[n][part * 8] = *(const f16x8_t*)&wt[(size_t)n * DIM + part * 8];
    }
    __syncthreads();

    f32x4_t acc[2][8];
#pragma unroll
    for (int a = 0; a < 2; ++a)
#pragma unroll
        for (int b = 0; b < 8; ++b) acc[a][b] = {0.f, 0.f, 0.f, 0.f};

#pragma unroll
    for (int s = 0; s < 2; ++s) {
        const int nb = s * DIM;
#pragma unroll
        for (int k2 = 0; k2 < 4; ++k2) {
            const int kg = (k2 << 5) + quad * 8;
            f16x8_t B[8];
#pragma unroll
            for (int jt = 0; jt < 8; ++jt)
                B[jt] = *(const f16x8_t*)&sW[nb + jt * 16 + m][kg];
#pragma unroll
            for (int rt = 0; rt < 2; ++rt) {
#pragma unroll
                for (int jt = 0; jt < 8; ++jt)
                    acc[rt][jt] = __builtin_amdgcn_mfma_f32_16x16x32_f16(aF[s][rt][k2], B[jt], acc[rt][jt], 0, 0, 0);
            }
        }
    }

    // epilogue: C/D layout col=lane&15, row=quad*4+reg  [m89-verified]
#pragma unroll
    for (int rt = 0; rt < 2; ++rt)
#pragma unroll
        for (int jt = 0; jt < 8; ++jt) {
            int col = jt * 16 + m;
            float bv = bias[col];
#pragma unroll
            for (int r4 = 0; r4 < 4; ++r4) {
                int row = rowW + rt * 16 + quad * 4 + r4;
                if (row >= N_NODES) continue;
                float v = acc[rt][jt][r4] + bv;
                if (relu) v = fmaxf(v, 0.f);
                if (write_f32) {
                    fout[(size_t)row * DIM + col] = v;
                } else {
                    h[(size_t)row * DIM + col] = (half_t)v;
                }
            }
        }
}

// ---------------- launch ----------------

extern "C" void kernel_launch(void* const* d_in, const int* in_sizes, int n_in,
                              void* d_out, int out_size, void* d_ws, size_t ws_size,
                              hipStream_t stream) {
    const float* x      = (const float*)d_in[0];
    const int*   src    = (const int*)d_in[1];
    const int*   dst    = (const int*)d_in[2];
    const float* w_self = (const float*)d_in[3];
    const float* w_neigh= (const float*)d_in[4];
    const float* b      = (const float*)d_in[5];
    float* out = (float*)d_out;

    // workspace carve (~31 MB)
    char* ws = (char*)d_ws;
    half_t* h    = (half_t*)ws;  ws += (size_t)N_NODES * DIM * 2;
    half_t* agg  = (half_t*)ws;  ws += (size_t)N_NODES * DIM * 2;
    half_t* wt   = (half_t*)ws;  ws += (size_t)N_LAYERS * 2 * DIM * DIM * 2;
    int*   cnt   = (int*)ws;     ws += (size_t)N_NODES * 4;
    int*   pcsr  = (int*)ws;     ws += (size_t)N_NODES * STRIDE * 4;

    hipMemsetAsync(cnt, 0, (size_t)N_NODES * 4, stream);

    const int SB = (N_EDGES / 2 + 255) / 256;  // 1250
    const int PREP_ITEMS = N_NODES * DIM / 8 + N_LAYERS * 2 * DIM * DIM;
    const int PB = (PREP_ITEMS + 255) / 256;   // 2884
    scatterprep_kernel<<<SB + PB, 256, 0, stream>>>(src, dst, cnt, pcsr,
                                                    x, h, w_self, w_neigh, wt);

    const int GEMM_BLOCKS = (N_NODES + 127) / 128;  // 313
    for (int l = 0; l < N_LAYERS; ++l) {
        agg_kernel<<<2048, 256, 0, stream>>>(h, cnt, pcsr, agg);
        int last = (l == N_LAYERS - 1);
        gemm_kernel<<<GEMM_BLOCKS, 256, 0, stream>>>(
            h, agg, wt + (size_t)l * 2 * DIM * DIM, b + (size_t)l * DIM,
            out, last ? 1 : 0, last ? 0 : 1);
    }
}

// Round 15
// 220.981 us; speedup vs baseline: 1.0662x; 1.0279x over previous
//
#include <hip/hip_runtime.h>

#define N_NODES 40000
#define N_EDGES 640000
#define DIM 128
#define N_LAYERS 3
#define STRIDE 64  // padded-CSR row stride; P(deg>64) ~ e^-40 under Poisson(16)

typedef _Float16 half_t;
typedef __attribute__((ext_vector_type(8))) _Float16 f16x8_t;
typedef __attribute__((ext_vector_type(4))) float f32x4_t;

// ---------------- fused preprocessing ----------------
// blocks [0, SB): padded-CSR scatter, 2 independent edges per thread (2x atomic MLP)
// blocks [SB, ...): x -> fp16 cast, W[k][n] f32 -> Wt[l][s][n][k] f16 transpose
__global__ void scatterprep_kernel(const int* __restrict__ src, const int* __restrict__ dst,
                                   int* __restrict__ cnt, int* __restrict__ pcsr,
                                   const float* __restrict__ x, half_t* __restrict__ h,
                                   const float* __restrict__ w_self, const float* __restrict__ w_neigh,
                                   half_t* __restrict__ wt) {
    const int HALF = N_EDGES / 2;  // 320000
    const int SB = (HALF + 255) / 256;  // 1250
    if (blockIdx.x < SB) {
        int i = blockIdx.x * 256 + threadIdx.x;
        if (i < HALF) {
            // two independent edge chains -> 2 atomics + 2 scatters in flight
            int d0 = dst[i], d1 = dst[i + HALF];
            int s0 = src[i], s1 = src[i + HALF];
            int p0 = atomicAdd(&cnt[d0], 1);
            int p1 = atomicAdd(&cnt[d1], 1);
            if (p0 < STRIDE) pcsr[d0 * STRIDE + p0] = s0;
            if (p1 < STRIDE) pcsr[d1 * STRIDE + p1] = s1;
        }
        return;
    }
    int i = (blockIdx.x - SB) * 256 + threadIdx.x;
    const int NS = N_NODES * DIM / 8;  // 640000 8-float chunks
    if (i < NS) {
        const float4* p = (const float4*)x + (size_t)i * 2;
        float4 a = p[0], b2 = p[1];
        f16x8_t v;
        v[0] = (half_t)a.x;  v[1] = (half_t)a.y;  v[2] = (half_t)a.z;  v[3] = (half_t)a.w;
        v[4] = (half_t)b2.x; v[5] = (half_t)b2.y; v[6] = (half_t)b2.z; v[7] = (half_t)b2.w;
        *(f16x8_t*)&h[(size_t)i * 8] = v;
    } else {
        int j = i - NS;
        if (j < N_LAYERS * 2 * DIM * DIM) {
            int k = j & (DIM - 1);
            int n = (j >> 7) & (DIM - 1);
            int ls = j >> 14;
            int l = ls >> 1, s = ls & 1;
            const float* W = (s ? w_neigh : w_self) + (size_t)l * DIM * DIM;
            wt[j] = (half_t)W[k * DIM + n];  // transposed: Wt[n][k]
        }
    }
}

// ---------------- mean aggregation: fp16 gather, index-hoisted, grid-strided ----------------
// Upfront per node: lane l holds pcsr[e0+l] and validity (1.0/0.0); chunk loop gets
// both via __shfl (ee <= 63 always since base <= 48), only in-loop mem op = 16B row load.
// fmaf(f32,(float)f16,f32) compiles to v_fma_mix (no separate cvt).
__global__ void agg_kernel(const half_t* __restrict__ h, const int* __restrict__ cnt,
                           const int* __restrict__ pcsr, half_t* __restrict__ agg) {
    const int gw = (blockIdx.x * blockDim.x + threadIdx.x) >> 6;
    const int nw = (gridDim.x * blockDim.x) >> 6;
    const int lane = threadIdx.x & 63;
    const int g = lane >> 4, c = lane & 15;  // edge-group, 16B column chunk

    for (int node = gw; node < N_NODES; node += nw) {
        int deg = cnt[node];
        int nd = deg < STRIDE ? deg : STRIDE;
        int il = (lane < nd) ? pcsr[node * STRIDE + lane] : 0;
        float fl = (lane < nd) ? 1.f : 0.f;

        float acc[8] = {0.f, 0.f, 0.f, 0.f, 0.f, 0.f, 0.f, 0.f};
        for (int base = 0; base < nd; base += 16) {
            float f[4];
            int sidx[4];
            f16x8_t v[4];
#pragma unroll
            for (int s = 0; s < 4; ++s) {
                int ee = base + 4 * s + g;   // <= 63 by construction (base <= 48)
                sidx[s] = __shfl(il, ee, 64);
                f[s] = __shfl(fl, ee, 64);
                v[s] = *(const f16x8_t*)&h[(size_t)sidx[s] * DIM + c * 8];
            }
#pragma unroll
            for (int s = 0; s < 4; ++s)
#pragma unroll
                for (int j = 0; j < 8; ++j)
                    acc[j] = fmaf(f[s], (float)v[s][j], acc[j]);  // -> v_fma_mix
        }
#pragma unroll
        for (int j = 0; j < 8; ++j) {
            acc[j] += __shfl_xor(acc[j], 16, 64);
            acc[j] += __shfl_xor(acc[j], 32, 64);
        }
        if (g == 0) {
            float w = 1.0f / fmaxf((float)deg, 1.0f);
            f16x8_t o;
#pragma unroll
            for (int j = 0; j < 8; ++j) o[j] = (half_t)(acc[j] * w);
            *(f16x8_t*)&agg[(size_t)node * DIM + c * 8] = o;
        }
    }
}

// ---------------- fused dual GEMM, single-pass fp16 MFMA ----------------
// out = h @ Wself + agg @ Wneigh + b. r14: 512 thr = 8 waves per 128x128 tile
// (wave = 16 rows x 8 jt), dual W stage (70 KB, ONE barrier) -> 2 blocks/CU but
// 4 waves/SIMD (vs 2 at 256 thr) to hide A-load + staging latency without r12's
// serialization. LDSN=140: row stride 280B = 70 dwords = 6 banks mod 32 -> 16
// distinct start banks across the wave (vs 8 at LDSN=136, which profiled 320K
// LDS bank conflicts/dispatch).
// In-place h update safe: each WAVE reads/writes only its own 16 rows.
#define LDSN 140
__global__ __launch_bounds__(512) void gemm_kernel(
    half_t* __restrict__ h, const half_t* __restrict__ agg,
    const half_t* __restrict__ wt,  // this layer: [2][128][128] (n-major, k contiguous)
    const float* __restrict__ bias, float* __restrict__ fout,
    int write_f32, int relu) {
    __shared__ half_t sW[2 * DIM][LDSN];  // 70 KB
    const int tid = threadIdx.x;
    const int wave = tid >> 6, lane = tid & 63;
    const int quad = lane >> 4, m = lane & 15;
    const int rowW = blockIdx.x * 128 + wave * 16;

    // stage both W matrices, full K (4096 16B chunks / 512 threads = 8 each)
#pragma unroll
    for (int c8 = 0; c8 < 8; ++c8) {
        int c = (c8 << 9) + tid;
        int part = c & 15;   // 16B chunk within 256B row
        int n = c >> 4;      // 0..255 = s*128+n
        *(f16x8_t*)&sW[n][part * 8] = *(const f16x8_t*)&wt[(size_t)n * DIM + part * 8];
    }
    __syncthreads();

    f32x4_t acc[8];
#pragma unroll
    for (int b = 0; b < 8; ++b) acc[b] = {0.f, 0.f, 0.f, 0.f};

#pragma unroll
    for (int s = 0; s < 2; ++s) {
        const half_t* A = s ? agg : h;
        const int nb = s * DIM;
#pragma unroll
        for (int k2 = 0; k2 < 4; ++k2) {
            const int kg = (k2 << 5) + quad * 8;
            f16x8_t B[8];
#pragma unroll
            for (int jt = 0; jt < 8; ++jt)
                B[jt] = *(const f16x8_t*)&sW[nb + jt * 16 + m][kg];
            int r = rowW + m;
            r = (r < N_NODES) ? r : (N_NODES - 1);  // clamp; stores guarded later
            f16x8_t a = *(const f16x8_t*)&A[(size_t)r * DIM + kg];
#pragma unroll
            for (int jt = 0; jt < 8; ++jt)
                acc[jt] = __builtin_amdgcn_mfma_f32_16x16x32_f16(a, B[jt], acc[jt], 0, 0, 0);
        }
    }

    // epilogue: C/D layout col=lane&15, row=quad*4+reg  [m89-verified]
#pragma unroll
    for (int jt = 0; jt < 8; ++jt) {
        int col = jt * 16 + m;
        float bv = bias[col];
#pragma unroll
        for (int r4 = 0; r4 < 4; ++r4) {
            int row = rowW + quad * 4 + r4;
            if (row >= N_NODES) continue;
            float v = acc[jt][r4] + bv;
            if (relu) v = fmaxf(v, 0.f);
            if (write_f32) {
                fout[(size_t)row * DIM + col] = v;
            } else {
                h[(size_t)row * DIM + col] = (half_t)v;
            }
        }
    }
}

// ---------------- launch ----------------

extern "C" void kernel_launch(void* const* d_in, const int* in_sizes, int n_in,
                              void* d_out, int out_size, void* d_ws, size_t ws_size,
                              hipStream_t stream) {
    const float* x      = (const float*)d_in[0];
    const int*   src    = (const int*)d_in[1];
    const int*   dst    = (const int*)d_in[2];
    const float* w_self = (const float*)d_in[3];
    const float* w_neigh= (const float*)d_in[4];
    const float* b      = (const float*)d_in[5];
    float* out = (float*)d_out;

    // workspace carve (~31 MB)
    char* ws = (char*)d_ws;
    half_t* h    = (half_t*)ws;  ws += (size_t)N_NODES * DIM * 2;
    half_t* agg  = (half_t*)ws;  ws += (size_t)N_NODES * DIM * 2;
    half_t* wt   = (half_t*)ws;  ws += (size_t)N_LAYERS * 2 * DIM * DIM * 2;
    int*   cnt   = (int*)ws;     ws += (size_t)N_NODES * 4;
    int*   pcsr  = (int*)ws;     ws += (size_t)N_NODES * STRIDE * 4;

    hipMemsetAsync(cnt, 0, (size_t)N_NODES * 4, stream);

    const int SB = (N_EDGES / 2 + 255) / 256;  // 1250
    const int PREP_ITEMS = N_NODES * DIM / 8 + N_LAYERS * 2 * DIM * DIM;
    const int PB = (PREP_ITEMS + 255) / 256;   // 2884
    scatterprep_kernel<<<SB + PB, 256, 0, stream>>>(src, dst, cnt, pcsr,
                                                    x, h, w_self, w_neigh, wt);

    const int GEMM_BLOCKS = (N_NODES + 127) / 128;  // 313
    for (int l = 0; l < N_LAYERS; ++l) {
        agg_kernel<<<2048, 256, 0, stream>>>(h, cnt, pcsr, agg);
        int last = (l == N_LAYERS - 1);
        gemm_kernel<<<GEMM_BLOCKS, 512, 0, stream>>>(
            h, agg, wt + (size_t)l * 2 * DIM * DIM, b + (size_t)l * DIM,
            out, last ? 1 : 0, last ? 0 : 1);
    }
}

// Round 16
// 219.123 us; speedup vs baseline: 1.0752x; 1.0085x over previous
//
#include <hip/hip_runtime.h>

#define N_NODES 40000
#define N_EDGES 640000
#define DIM 128
#define N_LAYERS 3
#define STRIDE 64  // padded-CSR row stride; P(deg>64) ~ e^-40 under Poisson(16)

typedef _Float16 half_t;
typedef __attribute__((ext_vector_type(8))) _Float16 f16x8_t;
typedef __attribute__((ext_vector_type(4))) float f32x4_t;

// ---------------- fused preprocessing ----------------
// blocks [0, SB): padded-CSR scatter, 4 independent edges per thread (4x atomic MLP:
// the atomicAdd->scattered-store chain is ~2x900cyc; 4 chains in flight hide it)
// blocks [SB, ...): x -> fp16 cast, W[k][n] f32 -> Wt[l][s][n][k] f16 transpose
__global__ void scatterprep_kernel(const int* __restrict__ src, const int* __restrict__ dst,
                                   int* __restrict__ cnt, int* __restrict__ pcsr,
                                   const float* __restrict__ x, half_t* __restrict__ h,
                                   const float* __restrict__ w_self, const float* __restrict__ w_neigh,
                                   half_t* __restrict__ wt) {
    const int QTR = N_EDGES / 4;  // 160000
    const int SB = (QTR + 255) / 256;  // 625
    if (blockIdx.x < SB) {
        int i = blockIdx.x * 256 + threadIdx.x;
        if (i < QTR) {
            int d0 = dst[i],           s0 = src[i];
            int d1 = dst[i + QTR],     s1 = src[i + QTR];
            int d2 = dst[i + 2 * QTR], s2 = src[i + 2 * QTR];
            int d3 = dst[i + 3 * QTR], s3 = src[i + 3 * QTR];
            int p0 = atomicAdd(&cnt[d0], 1);
            int p1 = atomicAdd(&cnt[d1], 1);
            int p2 = atomicAdd(&cnt[d2], 1);
            int p3 = atomicAdd(&cnt[d3], 1);
            if (p0 < STRIDE) pcsr[d0 * STRIDE + p0] = s0;
            if (p1 < STRIDE) pcsr[d1 * STRIDE + p1] = s1;
            if (p2 < STRIDE) pcsr[d2 * STRIDE + p2] = s2;
            if (p3 < STRIDE) pcsr[d3 * STRIDE + p3] = s3;
        }
        return;
    }
    int i = (blockIdx.x - SB) * 256 + threadIdx.x;
    const int NS = N_NODES * DIM / 8;  // 640000 8-float chunks
    if (i < NS) {
        const float4* p = (const float4*)x + (size_t)i * 2;
        float4 a = p[0], b2 = p[1];
        f16x8_t v;
        v[0] = (half_t)a.x;  v[1] = (half_t)a.y;  v[2] = (half_t)a.z;  v[3] = (half_t)a.w;
        v[4] = (half_t)b2.x; v[5] = (half_t)b2.y; v[6] = (half_t)b2.z; v[7] = (half_t)b2.w;
        *(f16x8_t*)&h[(size_t)i * 8] = v;
    } else {
        int j = i - NS;
        if (j < N_LAYERS * 2 * DIM * DIM) {
            int k = j & (DIM - 1);
            int n = (j >> 7) & (DIM - 1);
            int ls = j >> 14;
            int l = ls >> 1, s = ls & 1;
            const float* W = (s ? w_neigh : w_self) + (size_t)l * DIM * DIM;
            wt[j] = (half_t)W[k * DIM + n];  // transposed: Wt[n][k]
        }
    }
}

// ---------------- mean aggregation: fp16 gather, index-hoisted, grid-strided ----------------
// Upfront per node: lane l holds pcsr[e0+l] and validity (1.0/0.0); chunk loop gets
// both via __shfl (ee <= 63 always since base <= 48), only in-loop mem op = 16B row load.
// fmaf(f32,(float)f16,f32) compiles to v_fma_mix (no separate cvt).
__global__ void agg_kernel(const half_t* __restrict__ h, const int* __restrict__ cnt,
                           const int* __restrict__ pcsr, half_t* __restrict__ agg) {
    const int gw = (blockIdx.x * blockDim.x + threadIdx.x) >> 6;
    const int nw = (gridDim.x * blockDim.x) >> 6;
    const int lane = threadIdx.x & 63;
    const int g = lane >> 4, c = lane & 15;  // edge-group, 16B column chunk

    for (int node = gw; node < N_NODES; node += nw) {
        int deg = cnt[node];
        int nd = deg < STRIDE ? deg : STRIDE;
        int il = (lane < nd) ? pcsr[node * STRIDE + lane] : 0;
        float fl = (lane < nd) ? 1.f : 0.f;

        float acc[8] = {0.f, 0.f, 0.f, 0.f, 0.f, 0.f, 0.f, 0.f};
        for (int base = 0; base < nd; base += 16) {
            float f[4];
            int sidx[4];
            f16x8_t v[4];
#pragma unroll
            for (int s = 0; s < 4; ++s) {
                int ee = base + 4 * s + g;   // <= 63 by construction (base <= 48)
                sidx[s] = __shfl(il, ee, 64);
                f[s] = __shfl(fl, ee, 64);
                v[s] = *(const f16x8_t*)&h[(size_t)sidx[s] * DIM + c * 8];
            }
#pragma unroll
            for (int s = 0; s < 4; ++s)
#pragma unroll
                for (int j = 0; j < 8; ++j)
                    acc[j] = fmaf(f[s], (float)v[s][j], acc[j]);  // -> v_fma_mix
        }
#pragma unroll
        for (int j = 0; j < 8; ++j) {
            acc[j] += __shfl_xor(acc[j], 16, 64);
            acc[j] += __shfl_xor(acc[j], 32, 64);
        }
        if (g == 0) {
            float w = 1.0f / fmaxf((float)deg, 1.0f);
            f16x8_t o;
#pragma unroll
            for (int j = 0; j < 8; ++j) o[j] = (half_t)(acc[j] * w);
            *(f16x8_t*)&agg[(size_t)node * DIM + c * 8] = o;
        }
    }
}

// ---------------- fused dual GEMM, single-pass fp16 MFMA ----------------
// out = h @ Wself + agg @ Wneigh + b. 512 thr = 8 waves per 128x128 tile
// (wave = 16 rows x 8 jt), dual W stage (70 KB, ONE barrier) -> 2 blocks/CU,
// 4 waves/SIMD to hide A-load + staging latency. LDSN=140: row stride 280B =
// 6 banks mod 32 -> 16 distinct start banks (vs 8 at 136, which profiled 320K
// LDS bank conflicts/dispatch).
// In-place h update safe: each WAVE reads/writes only its own 16 rows.
#define LDSN 140
__global__ __launch_bounds__(512) void gemm_kernel(
    half_t* __restrict__ h, const half_t* __restrict__ agg,
    const half_t* __restrict__ wt,  // this layer: [2][128][128] (n-major, k contiguous)
    const float* __restrict__ bias, float* __restrict__ fout,
    int write_f32, int relu) {
    __shared__ half_t sW[2 * DIM][LDSN];  // 70 KB
    const int tid = threadIdx.x;
    const int wave = tid >> 6, lane = tid & 63;
    const int quad = lane >> 4, m = lane & 15;
    const int rowW = blockIdx.x * 128 + wave * 16;

    // stage both W matrices, full K (4096 16B chunks / 512 threads = 8 each)
#pragma unroll
    for (int c8 = 0; c8 < 8; ++c8) {
        int c = (c8 << 9) + tid;
        int part = c & 15;   // 16B chunk within 256B row
        int n = c >> 4;      // 0..255 = s*128+n
        *(f16x8_t*)&sW[n][part * 8] = *(const f16x8_t*)&wt[(size_t)n * DIM + part * 8];
    }
    __syncthreads();

    f32x4_t acc[8];
#pragma unroll
    for (int b = 0; b < 8; ++b) acc[b] = {0.f, 0.f, 0.f, 0.f};

#pragma unroll
    for (int s = 0; s < 2; ++s) {
        const half_t* A = s ? agg : h;
        const int nb = s * DIM;
#pragma unroll
        for (int k2 = 0; k2 < 4; ++k2) {
            const int kg = (k2 << 5) + quad * 8;
            f16x8_t B[8];
#pragma unroll
            for (int jt = 0; jt < 8; ++jt)
                B[jt] = *(const f16x8_t*)&sW[nb + jt * 16 + m][kg];
            int r = rowW + m;
            r = (r < N_NODES) ? r : (N_NODES - 1);  // clamp; stores guarded later
            f16x8_t a = *(const f16x8_t*)&A[(size_t)r * DIM + kg];
#pragma unroll
            for (int jt = 0; jt < 8; ++jt)
                acc[jt] = __builtin_amdgcn_mfma_f32_16x16x32_f16(a, B[jt], acc[jt], 0, 0, 0);
        }
    }

    // epilogue: C/D layout col=lane&15, row=quad*4+reg  [m89-verified]
#pragma unroll
    for (int jt = 0; jt < 8; ++jt) {
        int col = jt * 16 + m;
        float bv = bias[col];
#pragma unroll
        for (int r4 = 0; r4 < 4; ++r4) {
            int row = rowW + quad * 4 + r4;
            if (row >= N_NODES) continue;
            float v = acc[jt][r4] + bv;
            if (relu) v = fmaxf(v, 0.f);
            if (write_f32) {
                fout[(size_t)row * DIM + col] = v;
            } else {
                h[(size_t)row * DIM + col] = (half_t)v;
            }
        }
    }
}

// ---------------- launch ----------------

extern "C" void kernel_launch(void* const* d_in, const int* in_sizes, int n_in,
                              void* d_out, int out_size, void* d_ws, size_t ws_size,
                              hipStream_t stream) {
    const float* x      = (const float*)d_in[0];
    const int*   src    = (const int*)d_in[1];
    const int*   dst    = (const int*)d_in[2];
    const float* w_self = (const float*)d_in[3];
    const float* w_neigh= (const float*)d_in[4];
    const float* b      = (const float*)d_in[5];
    float* out = (float*)d_out;

    // workspace carve (~31 MB)
    char* ws = (char*)d_ws;
    half_t* h    = (half_t*)ws;  ws += (size_t)N_NODES * DIM * 2;
    half_t* agg  = (half_t*)ws;  ws += (size_t)N_NODES * DIM * 2;
    half_t* wt   = (half_t*)ws;  ws += (size_t)N_LAYERS * 2 * DIM * DIM * 2;
    int*   cnt   = (int*)ws;     ws += (size_t)N_NODES * 4;
    int*   pcsr  = (int*)ws;     ws += (size_t)N_NODES * STRIDE * 4;

    hipMemsetAsync(cnt, 0, (size_t)N_NODES * 4, stream);

    const int SB = (N_EDGES / 4 + 255) / 256;  // 625
    const int PREP_ITEMS = N_NODES * DIM / 8 + N_LAYERS * 2 * DIM * DIM;
    const int PB = (PREP_ITEMS + 255) / 256;   // 2884
    scatterprep_kernel<<<SB + PB, 256, 0, stream>>>(src, dst, cnt, pcsr,
                                                    x, h, w_self, w_neigh, wt);

    const int GEMM_BLOCKS = (N_NODES + 127) / 128;  // 313
    for (int l = 0; l < N_LAYERS; ++l) {
        agg_kernel<<<2048, 256, 0, stream>>>(h, cnt, pcsr, agg);
        int last = (l == N_LAYERS - 1);
        gemm_kernel<<<GEMM_BLOCKS, 512, 0, stream>>>(
            h, agg, wt + (size_t)l * 2 * DIM * DIM, b + (size_t)l * DIM,
            out, last ? 1 : 0, last ? 0 : 1);
    }
}

// Round 17
// 215.448 us; speedup vs baseline: 1.0936x; 1.0171x over previous
//
#include <hip/hip_runtime.h>

#define N_NODES 40000
#define N_EDGES 640000
#define DIM 128
#define N_LAYERS 3
#define STRIDE 64  // padded-CSR row stride; P(deg>64) ~ e^-40 under Poisson(16)

typedef _Float16 half_t;
typedef __attribute__((ext_vector_type(8))) _Float16 f16x8_t;
typedef __attribute__((ext_vector_type(4))) float f32x4_t;
typedef __attribute__((ext_vector_type(2))) float f32x2_t;

// ---------------- fused preprocessing ----------------
// blocks [0, SB): padded-CSR scatter, 4 independent edges per thread (4x atomic MLP)
// blocks [SB, ...): x -> fp16 h + fp8(e4m3) h8, W[k][n] f32 -> Wt[l][s][n][k] f16
__global__ void scatterprep_kernel(const int* __restrict__ src, const int* __restrict__ dst,
                                   int* __restrict__ cnt, int* __restrict__ pcsr,
                                   const float* __restrict__ x, half_t* __restrict__ h,
                                   unsigned char* __restrict__ h8,
                                   const float* __restrict__ w_self, const float* __restrict__ w_neigh,
                                   half_t* __restrict__ wt) {
    const int QTR = N_EDGES / 4;  // 160000
    const int SB = (QTR + 255) / 256;  // 625
    if (blockIdx.x < SB) {
        int i = blockIdx.x * 256 + threadIdx.x;
        if (i < QTR) {
            int d0 = dst[i],           s0 = src[i];
            int d1 = dst[i + QTR],     s1 = src[i + QTR];
            int d2 = dst[i + 2 * QTR], s2 = src[i + 2 * QTR];
            int d3 = dst[i + 3 * QTR], s3 = src[i + 3 * QTR];
            int p0 = atomicAdd(&cnt[d0], 1);
            int p1 = atomicAdd(&cnt[d1], 1);
            int p2 = atomicAdd(&cnt[d2], 1);
            int p3 = atomicAdd(&cnt[d3], 1);
            if (p0 < STRIDE) pcsr[d0 * STRIDE + p0] = s0;
            if (p1 < STRIDE) pcsr[d1 * STRIDE + p1] = s1;
            if (p2 < STRIDE) pcsr[d2 * STRIDE + p2] = s2;
            if (p3 < STRIDE) pcsr[d3 * STRIDE + p3] = s3;
        }
        return;
    }
    int i = (blockIdx.x - SB) * 256 + threadIdx.x;
    const int NS = N_NODES * DIM / 8;  // 640000 8-float chunks
    if (i < NS) {
        const float4* p = (const float4*)x + (size_t)i * 2;
        float4 a = p[0], b2 = p[1];
        float v[8] = {a.x, a.y, a.z, a.w, b2.x, b2.y, b2.z, b2.w};
        f16x8_t hv;
#pragma unroll
        for (int j = 0; j < 8; ++j) hv[j] = (half_t)v[j];
        *(f16x8_t*)&h[(size_t)i * 8] = hv;
        // fp8 e4m3 copy for the aggregation gather (halves gather bytes, no scale)
        unsigned int lo = __builtin_amdgcn_cvt_pk_fp8_f32(v[0], v[1], 0, false);
        lo = __builtin_amdgcn_cvt_pk_fp8_f32(v[2], v[3], lo, true);
        unsigned int hi = __builtin_amdgcn_cvt_pk_fp8_f32(v[4], v[5], 0, false);
        hi = __builtin_amdgcn_cvt_pk_fp8_f32(v[6], v[7], hi, true);
        uint2 pk; pk.x = lo; pk.y = hi;
        *(uint2*)&h8[(size_t)i * 8] = pk;
    } else {
        int j = i - NS;
        if (j < N_LAYERS * 2 * DIM * DIM) {
            int k = j & (DIM - 1);
            int n = (j >> 7) & (DIM - 1);
            int ls = j >> 14;
            int l = ls >> 1, s = ls & 1;
            const float* W = (s ? w_neigh : w_self) + (size_t)l * DIM * DIM;
            wt[j] = (half_t)W[k * DIM + n];  // transposed: Wt[n][k]
        }
    }
}

// ---------------- mean aggregation: fp8 gather (128B rows), fp32 accumulate ----------------
// one wave per node per grid-stride iter; 16 lanes per row (8B uint2 each), 4 edge-groups,
// 16 edges in flight. Index+mask hoisted upfront (coalesced pcsr load, __shfl in-loop).
// Decode: v_cvt_pk_f32_fp8 (2 elems/op, HW) + fma -> 1.5 VALU ops/elem; gather bytes
// halved vs fp16 with ZERO side traffic (no per-row scale needed for e4m3 range).
__global__ void agg_kernel(const unsigned char* __restrict__ h8, const int* __restrict__ cnt,
                           const int* __restrict__ pcsr, half_t* __restrict__ agg) {
    const int gw = (blockIdx.x * blockDim.x + threadIdx.x) >> 6;
    const int nw = (gridDim.x * blockDim.x) >> 6;
    const int lane = threadIdx.x & 63;
    const int g = lane >> 4, c = lane & 15;  // edge-group, 8B column chunk

    for (int node = gw; node < N_NODES; node += nw) {
        int deg = cnt[node];
        int nd = deg < STRIDE ? deg : STRIDE;
        int il = (lane < nd) ? pcsr[node * STRIDE + lane] : 0;
        float fl = (lane < nd) ? 1.f : 0.f;

        float acc[8] = {0.f, 0.f, 0.f, 0.f, 0.f, 0.f, 0.f, 0.f};
        for (int base = 0; base < nd; base += 16) {
            float f[4];
            int sidx[4];
            uint2 q[4];
#pragma unroll
            for (int s = 0; s < 4; ++s) {
                int ee = base + 4 * s + g;   // <= 63 by construction (base <= 48)
                sidx[s] = __shfl(il, ee, 64);
                f[s] = __shfl(fl, ee, 64);
                q[s] = *(const uint2*)&h8[(size_t)sidx[s] * DIM + c * 8];
            }
#pragma unroll
            for (int s = 0; s < 4; ++s) {
                f32x2_t p0 = __builtin_amdgcn_cvt_pk_f32_fp8(q[s].x, false);
                f32x2_t p1 = __builtin_amdgcn_cvt_pk_f32_fp8(q[s].x, true);
                f32x2_t p2 = __builtin_amdgcn_cvt_pk_f32_fp8(q[s].y, false);
                f32x2_t p3 = __builtin_amdgcn_cvt_pk_f32_fp8(q[s].y, true);
                acc[0] = fmaf(f[s], p0.x, acc[0]);
                acc[1] = fmaf(f[s], p0.y, acc[1]);
                acc[2] = fmaf(f[s], p1.x, acc[2]);
                acc[3] = fmaf(f[s], p1.y, acc[3]);
                acc[4] = fmaf(f[s], p2.x, acc[4]);
                acc[5] = fmaf(f[s], p2.y, acc[5]);
                acc[6] = fmaf(f[s], p3.x, acc[6]);
                acc[7] = fmaf(f[s], p3.y, acc[7]);
            }
        }
#pragma unroll
        for (int j = 0; j < 8; ++j) {
            acc[j] += __shfl_xor(acc[j], 16, 64);
            acc[j] += __shfl_xor(acc[j], 32, 64);
        }
        if (g == 0) {
            float w = 1.0f / fmaxf((float)deg, 1.0f);
            f16x8_t o;
#pragma unroll
            for (int j = 0; j < 8; ++j) o[j] = (half_t)(acc[j] * w);
            *(f16x8_t*)&agg[(size_t)node * DIM + c * 8] = o;
        }
    }
}

// ---------------- fused dual GEMM, single-pass fp16 MFMA ----------------
// 512 thr = 8 waves per 128x128 tile (wave = 16 rows x 8 jt), dual W stage (70 KB,
// one barrier), LDSN=140 bank-phase fix. Epilogue (non-last layers) additionally
// repacks the new h rows to fp8 via reused LDS (sW dead after the k-loop).
// In-place h update safe: each WAVE reads/writes only its own 16 rows.
#define LDSN 140
#define SCRP 132   // repack scratch stride (halves)
__global__ __launch_bounds__(512) void gemm_kernel(
    half_t* __restrict__ h, const half_t* __restrict__ agg,
    const half_t* __restrict__ wt,  // this layer: [2][128][128] (n-major, k contiguous)
    const float* __restrict__ bias, float* __restrict__ fout,
    unsigned char* __restrict__ h8, int write_f32, int relu) {
    __shared__ half_t sW[2 * DIM][LDSN];  // 70 KB
    half_t (*sScr)[SCRP] = (half_t(*)[SCRP])sW;  // reused after k-loop (33 KB of it)
    const int tid = threadIdx.x;
    const int wave = tid >> 6, lane = tid & 63;
    const int quad = lane >> 4, m = lane & 15;
    const int rowW = blockIdx.x * 128 + wave * 16;

    // stage both W matrices, full K (4096 16B chunks / 512 threads = 8 each)
#pragma unroll
    for (int c8 = 0; c8 < 8; ++c8) {
        int c = (c8 << 9) + tid;
        int part = c & 15;   // 16B chunk within 256B row
        int n = c >> 4;      // 0..255 = s*128+n
        *(f16x8_t*)&sW[n][part * 8] = *(const f16x8_t*)&wt[(size_t)n * DIM + part * 8];
    }
    __syncthreads();

    f32x4_t acc[8];
#pragma unroll
    for (int b = 0; b < 8; ++b) acc[b] = {0.f, 0.f, 0.f, 0.f};

#pragma unroll
    for (int s = 0; s < 2; ++s) {
        const half_t* A = s ? agg : h;
        const int nb = s * DIM;
#pragma unroll
        for (int k2 = 0; k2 < 4; ++k2) {
            const int kg = (k2 << 5) + quad * 8;
            f16x8_t B[8];
#pragma unroll
            for (int jt = 0; jt < 8; ++jt)
                B[jt] = *(const f16x8_t*)&sW[nb + jt * 16 + m][kg];
            int r = rowW + m;
            r = (r < N_NODES) ? r : (N_NODES - 1);  // clamp; stores guarded later
            f16x8_t a = *(const f16x8_t*)&A[(size_t)r * DIM + kg];
#pragma unroll
            for (int jt = 0; jt < 8; ++jt)
                acc[jt] = __builtin_amdgcn_mfma_f32_16x16x32_f16(a, B[jt], acc[jt], 0, 0, 0);
        }
    }

    __syncthreads();  // all waves done reading sW before LDS reuse

    // epilogue: C/D layout col=lane&15, row=quad*4+reg  [m89-verified]
#pragma unroll
    for (int jt = 0; jt < 8; ++jt) {
        int col = jt * 16 + m;
        float bv = bias[col];
#pragma unroll
        for (int r4 = 0; r4 < 4; ++r4) {
            int rloc = wave * 16 + quad * 4 + r4;
            int row = blockIdx.x * 128 + rloc;
            if (row >= N_NODES) continue;
            float v = acc[jt][r4] + bv;
            if (relu) v = fmaxf(v, 0.f);
            if (write_f32) {
                fout[(size_t)row * DIM + col] = v;
            } else {
                half_t hv = (half_t)v;
                h[(size_t)row * DIM + col] = hv;
                sScr[rloc][col] = hv;
            }
        }
    }

    if (!write_f32) {
        __syncthreads();
        // fp8 repack: thread t handles a quarter-row (32 elems -> 32 B)
        int rl = tid >> 2, qr = tid & 3;
        int row = blockIdx.x * 128 + rl;
        if (row < N_NODES) {
            unsigned int u[8];
#pragma unroll
            for (int k8 = 0; k8 < 4; ++k8) {
                f16x8_t vv = *(const f16x8_t*)&sScr[rl][qr * 32 + k8 * 8];
                unsigned int a0 = __builtin_amdgcn_cvt_pk_fp8_f32((float)vv[0], (float)vv[1], 0, false);
                a0 = __builtin_amdgcn_cvt_pk_fp8_f32((float)vv[2], (float)vv[3], a0, true);
                unsigned int a1 = __builtin_amdgcn_cvt_pk_fp8_f32((float)vv[4], (float)vv[5], 0, false);
                a1 = __builtin_amdgcn_cvt_pk_fp8_f32((float)vv[6], (float)vv[7], a1, true);
                u[k8 * 2] = a0;
                u[k8 * 2 + 1] = a1;
            }
            uint4 pk0 = {u[0], u[1], u[2], u[3]};
            uint4 pk1 = {u[4], u[5], u[6], u[7]};
            *(uint4*)&h8[(size_t)row * DIM + qr * 32] = pk0;
            *(uint4*)&h8[(size_t)row * DIM + qr * 32 + 16] = pk1;
        }
    }
}

// ---------------- launch ----------------

extern "C" void kernel_launch(void* const* d_in, const int* in_sizes, int n_in,
                              void* d_out, int out_size, void* d_ws, size_t ws_size,
                              hipStream_t stream) {
    const float* x      = (const float*)d_in[0];
    const int*   src    = (const int*)d_in[1];
    const int*   dst    = (const int*)d_in[2];
    const float* w_self = (const float*)d_in[3];
    const float* w_neigh= (const float*)d_in[4];
    const float* b      = (const float*)d_in[5];
    float* out = (float*)d_out;

    // workspace carve (~36 MB)
    char* ws = (char*)d_ws;
    half_t* h    = (half_t*)ws;  ws += (size_t)N_NODES * DIM * 2;
    half_t* agg  = (half_t*)ws;  ws += (size_t)N_NODES * DIM * 2;
    half_t* wt   = (half_t*)ws;  ws += (size_t)N_LAYERS * 2 * DIM * DIM * 2;
    unsigned char* h8 = (unsigned char*)ws; ws += (size_t)N_NODES * DIM;
    int*   cnt   = (int*)ws;     ws += (size_t)N_NODES * 4;
    int*   pcsr  = (int*)ws;     ws += (size_t)N_NODES * STRIDE * 4;

    hipMemsetAsync(cnt, 0, (size_t)N_NODES * 4, stream);

    const int SB = (N_EDGES / 4 + 255) / 256;  // 625
    const int PREP_ITEMS = N_NODES * DIM / 8 + N_LAYERS * 2 * DIM * DIM;
    const int PB = (PREP_ITEMS + 255) / 256;   // 2884
    scatterprep_kernel<<<SB + PB, 256, 0, stream>>>(src, dst, cnt, pcsr,
                                                    x, h, h8, w_self, w_neigh, wt);

    const int GEMM_BLOCKS = (N_NODES + 127) / 128;  // 313
    for (int l = 0; l < N_LAYERS; ++l) {
        agg_kernel<<<2048, 256, 0, stream>>>(h8, cnt, pcsr, agg);
        int last = (l == N_LAYERS - 1);
        gemm_kernel<<<GEMM_BLOCKS, 512, 0, stream>>>(
            h, agg, wt + (size_t)l * 2 * DIM * DIM, b + (size_t)l * DIM,
            out, h8, last ? 1 : 0, last ? 0 : 1);
    }
}